// Round 1
// baseline (8373.141 us; speedup 1.0000x reference)
//
#include <hip/hip_runtime.h>

#define NN 100000
#define NE 1600000
#define NP 500000
#define C 128

// One edge handled by 32 threads; each thread does a float4 load of the
// source row and 4 scalar atomicAdds into the destination row.
__global__ void scatter_add_kernel(const float* __restrict__ x,
                                   const int* __restrict__ src,
                                   const int* __restrict__ dst,
                                   float* __restrict__ agg,
                                   float* __restrict__ deg,
                                   int nEdges) {
    int gid = blockIdx.x * blockDim.x + threadIdx.x;
    int e = gid >> 5;
    if (e >= nEdges) return;
    int lane = gid & 31;
    int s = src[e];
    int d = dst[e];
    const float4* xs = (const float4*)(x + (size_t)s * C);
    float4 v = xs[lane];
    float* ad = agg + (size_t)d * C + lane * 4;
    atomicAdd(ad + 0, v.x);
    atomicAdd(ad + 1, v.y);
    atomicAdd(ad + 2, v.z);
    atomicAdd(ad + 3, v.w);
    if (deg != nullptr && lane == 0) atomicAdd(deg + d, 1.0f);
}

// out[node][t] = act( bias[t] + sum_k mean[k]*wl[k][t] + xin[node][k]*wr[k][t] )
// one block (128 threads) per node; mean and x row staged in LDS.
// Safe in-place (hout == xin): thread t reads only element t of its row.
__global__ void sage_layer_kernel(const float* __restrict__ agg,
                                  const float* __restrict__ deg,
                                  const float* __restrict__ xin,
                                  const float* __restrict__ wl,
                                  const float* __restrict__ bias,
                                  const float* __restrict__ wr,
                                  float* __restrict__ hout,
                                  int relu) {
    __shared__ float sm[C];
    __shared__ float sx[C];
    int node = blockIdx.x;
    int t = threadIdx.x;
    float dg = fmaxf(deg[node], 1.0f);
    size_t row = (size_t)node * C;
    sm[t] = agg[row + t] / dg;
    sx[t] = xin[row + t];
    __syncthreads();
    float acc = bias[t];
#pragma unroll 8
    for (int k = 0; k < C; ++k) {
        acc += sm[k] * wl[k * C + t] + sx[k] * wr[k * C + t];
    }
    if (relu) acc = fmaxf(acc, 0.0f);
    hout[row + t] = acc;
}

// out[p] = bd2 + sum_j relu(bd1[j] + sum_k feat[k]*wd1[k][j]) * wd2[j]
// feat = concat(h[u], h[v]); one block (128 threads) per pair.
__global__ void decode_kernel(const float* __restrict__ h,
                              const int* __restrict__ pu,
                              const int* __restrict__ pv,
                              const float* __restrict__ wd1,
                              const float* __restrict__ bd1,
                              const float* __restrict__ wd2,
                              const float* __restrict__ bd2,
                              float* __restrict__ out,
                              int nPairs) {
    __shared__ float feat[2 * C];
    __shared__ float wsum[2];
    int p = blockIdx.x;
    if (p >= nPairs) return;
    int t = threadIdx.x;
    int u = pu[p];
    int v = pv[p];
    feat[t] = h[(size_t)u * C + t];
    feat[C + t] = h[(size_t)v * C + t];
    __syncthreads();
    float acc = bd1[t];
#pragma unroll 8
    for (int k = 0; k < 2 * C; ++k) {
        acc += feat[k] * wd1[k * C + t];
    }
    acc = fmaxf(acc, 0.0f);
    float val = acc * wd2[t];
    // reduce over 128 threads (2 waves of 64)
    for (int off = 32; off > 0; off >>= 1) val += __shfl_down(val, off, 64);
    if ((t & 63) == 0) wsum[t >> 6] = val;
    __syncthreads();
    if (t == 0) out[p] = wsum[0] + wsum[1] + bd2[0];
}

extern "C" void kernel_launch(void* const* d_in, const int* in_sizes, int n_in,
                              void* d_out, int out_size, void* d_ws, size_t ws_size,
                              hipStream_t stream) {
    const float* x    = (const float*)d_in[0];
    const float* w1_l = (const float*)d_in[1];
    const float* b1   = (const float*)d_in[2];
    const float* w1_r = (const float*)d_in[3];
    const float* w2_l = (const float*)d_in[4];
    const float* b2   = (const float*)d_in[5];
    const float* w2_r = (const float*)d_in[6];
    const float* wd1  = (const float*)d_in[7];
    const float* bd1  = (const float*)d_in[8];
    const float* wd2  = (const float*)d_in[9];
    const float* bd2  = (const float*)d_in[10];
    const int* edge_index = (const int*)d_in[11];
    const int* edge_pairs = (const int*)d_in[12];

    // workspace layout (f32): deg[NN] | agg[NN*C] | h[NN*C]  (~103 MB)
    float* deg = (float*)d_ws;
    float* agg = deg + ((NN + 127) & ~127);
    float* h   = agg + (size_t)NN * C;

    const int* esrc = edge_index;
    const int* edst = edge_index + NE;
    const int* pu = edge_pairs;
    const int* pv = edge_pairs + NP;

    hipMemsetAsync(deg, 0, sizeof(float) * NN, stream);
    hipMemsetAsync(agg, 0, sizeof(float) * (size_t)NN * C, stream);

    int sblocks = (NE * 32 + 255) / 256;
    scatter_add_kernel<<<sblocks, 256, 0, stream>>>(x, esrc, edst, agg, deg, NE);
    sage_layer_kernel<<<NN, C, 0, stream>>>(agg, deg, x, w1_l, b1, w1_r, h, 1);

    hipMemsetAsync(agg, 0, sizeof(float) * (size_t)NN * C, stream);
    scatter_add_kernel<<<sblocks, 256, 0, stream>>>(h, esrc, edst, agg, nullptr, NE);
    sage_layer_kernel<<<NN, C, 0, stream>>>(agg, deg, h, w2_l, b2, w2_r, h, 0);

    decode_kernel<<<NP, C, 0, stream>>>(h, pu, pv, wd1, bd1, wd2, bd2,
                                        (float*)d_out, NP);
}

// Round 2
// 1807.815 us; speedup vs baseline: 4.6316x; 4.6316x over previous
//
#include <hip/hip_runtime.h>

#define NN 100000
#define NE 1600000
#define NP 500000
#define C 128
#define NB 8     // nodes per block in sage_fused (12500 blocks exactly)
#define PB 16    // pairs per block in decode (31250 blocks exactly)

// ---------- counting sort: histogram ----------
__global__ void hist_kernel(const int* __restrict__ dst, int* __restrict__ cnt, int nE) {
    int e = blockIdx.x * blockDim.x + threadIdx.x;
    if (e < nE) atomicAdd(&cnt[dst[e]], 1);
}

// ---------- single-block exclusive scan over NN ints (in place) ----------
__global__ void scan_kernel(int* __restrict__ cnt, int n) {
    __shared__ int tsum[1024];
    int tid = threadIdx.x;
    int chunk = (n + 1023) / 1024;
    int lo = tid * chunk;
    int hi = min(lo + chunk, n);
    int s = 0;
    for (int i = lo; i < hi; ++i) s += cnt[i];
    tsum[tid] = s;
    __syncthreads();
    // Hillis-Steele inclusive scan on tsum
    for (int off = 1; off < 1024; off <<= 1) {
        int v = (tid >= off) ? tsum[tid - off] : 0;
        __syncthreads();
        tsum[tid] += v;
        __syncthreads();
    }
    int base = (tid == 0) ? 0 : tsum[tid - 1];
    for (int i = lo; i < hi; ++i) {
        int c = cnt[i];
        cnt[i] = base;   // exclusive start offset
        base += c;
    }
}

// ---------- scatter src ids into CSR order; offs[i] becomes end-offset ----------
__global__ void scatter_sort_kernel(const int* __restrict__ src, const int* __restrict__ dst,
                                    int* __restrict__ offs, int* __restrict__ ssrc, int nE) {
    int e = blockIdx.x * blockDim.x + threadIdx.x;
    if (e >= nE) return;
    int pos = atomicAdd(&offs[dst[e]], 1);
    ssrc[pos] = src[e];
}

// ---------- fused mean-aggregate + SAGE layer ----------
// block = 256 threads, NB=8 nodes per block. thread = (group g = tid>>7, channel c = tid&127).
// Each group aggregates 4 nodes, then GEMV: out = mean@wl + b + x@wr.
__global__ void sage_fused_kernel(const float* __restrict__ xin,
                                  const int* __restrict__ offs,
                                  const int* __restrict__ ssrc,
                                  const float* __restrict__ wl,
                                  const float* __restrict__ bias,
                                  const float* __restrict__ wr,
                                  float* __restrict__ hout,
                                  int relu) {
    __shared__ float sm[NB][C];
    __shared__ float sx[NB][C];
    int c = threadIdx.x & (C - 1);
    int g = threadIdx.x >> 7;          // 0..1
    int node0 = blockIdx.x * NB;

    for (int i = 0; i < NB / 2; ++i) {
        int li = g * (NB / 2) + i;
        int n = node0 + li;
        if (n < NN) {
            int start = (n == 0) ? 0 : offs[n - 1];
            int end = offs[n];
            float acc = 0.0f;
            for (int e = start; e < end; ++e) {
                int s = ssrc[e];
                acc += xin[(size_t)s * C + c];
            }
            float dg = (float)(end - start);
            sm[li][c] = acc / fmaxf(dg, 1.0f);
            sx[li][c] = xin[(size_t)n * C + c];
        } else {
            sm[li][c] = 0.0f;
            sx[li][c] = 0.0f;
        }
    }
    __syncthreads();

    float acc[NB / 2];
    int nb0 = g * (NB / 2);
#pragma unroll
    for (int i = 0; i < NB / 2; ++i) acc[i] = bias[c];
#pragma unroll 4
    for (int k = 0; k < C; ++k) {
        float wlv = wl[k * C + c];
        float wrv = wr[k * C + c];
#pragma unroll
        for (int i = 0; i < NB / 2; ++i) {
            acc[i] += sm[nb0 + i][k] * wlv + sx[nb0 + i][k] * wrv;
        }
    }
#pragma unroll
    for (int i = 0; i < NB / 2; ++i) {
        int n = node0 + nb0 + i;
        if (n < NN) {
            float v = acc[i];
            if (relu) v = fmaxf(v, 0.0f);
            hout[(size_t)n * C + c] = v;
        }
    }
}

// ---------- tiled decode ----------
// block = 256 threads, PB=16 pairs. thread = (pgroup = tid>>7 -> 8 pairs, j = tid&127).
__global__ void decode_tiled_kernel(const float* __restrict__ h,
                                    const int* __restrict__ pu,
                                    const int* __restrict__ pv,
                                    const float* __restrict__ wd1,
                                    const float* __restrict__ bd1,
                                    const float* __restrict__ wd2,
                                    const float* __restrict__ bd2,
                                    float* __restrict__ out) {
    __shared__ float feat[PB][2 * C];  // 16 KB
    __shared__ float red[PB][2];
    int tid = threadIdx.x;
    int p0 = blockIdx.x * PB;

    // load feats: threads 0..127 cover h[u], 128..255 cover h[v]
    for (int p = 0; p < PB; ++p) {
        int pp = p0 + p;
        int node = (tid < C) ? pu[pp] : pv[pp];
        feat[p][tid] = h[(size_t)node * C + (tid & (C - 1))];
    }
    __syncthreads();

    int j = tid & (C - 1);
    int pg = tid >> 7;         // 0..1
    float acc[8];
    float b = bd1[j];
#pragma unroll
    for (int i = 0; i < 8; ++i) acc[i] = b;
#pragma unroll 4
    for (int k = 0; k < 2 * C; ++k) {
        float w = wd1[k * C + j];
#pragma unroll
        for (int i = 0; i < 8; ++i) acc[i] += feat[pg * 8 + i][k] * w;
    }

    float w2 = wd2[j];
    int jhalf = (tid >> 6) & 1;
#pragma unroll
    for (int i = 0; i < 8; ++i) {
        float v = fmaxf(acc[i], 0.0f) * w2;
        for (int off = 32; off > 0; off >>= 1) v += __shfl_down(v, off, 64);
        if ((tid & 63) == 0) red[pg * 8 + i][jhalf] = v;
    }
    __syncthreads();
    if (tid < PB) out[p0 + tid] = red[tid][0] + red[tid][1] + bd2[0];
}

extern "C" void kernel_launch(void* const* d_in, const int* in_sizes, int n_in,
                              void* d_out, int out_size, void* d_ws, size_t ws_size,
                              hipStream_t stream) {
    const float* x    = (const float*)d_in[0];
    const float* w1_l = (const float*)d_in[1];
    const float* b1   = (const float*)d_in[2];
    const float* w1_r = (const float*)d_in[3];
    const float* w2_l = (const float*)d_in[4];
    const float* b2   = (const float*)d_in[5];
    const float* w2_r = (const float*)d_in[6];
    const float* wd1  = (const float*)d_in[7];
    const float* bd1  = (const float*)d_in[8];
    const float* wd2  = (const float*)d_in[9];
    const float* bd2  = (const float*)d_in[10];
    const int* edge_index = (const int*)d_in[11];
    const int* edge_pairs = (const int*)d_in[12];

    const int* esrc = edge_index;
    const int* edst = edge_index + NE;
    const int* pu = edge_pairs;
    const int* pv = edge_pairs + NP;

    // workspace: offs[NN pad] | ssrc[NE] | h1[NN*C] | h2[NN*C]  (~109 MB)
    int* offs = (int*)d_ws;
    int* ssrc = offs + ((NN + 255) & ~255);
    float* h1 = (float*)(ssrc + ((NE + 255) & ~255));
    float* h2 = h1 + (size_t)NN * C;

    hipMemsetAsync(offs, 0, sizeof(int) * NN, stream);

    int eblocks = (NE + 255) / 256;
    hist_kernel<<<eblocks, 256, 0, stream>>>(edst, offs, NE);
    scan_kernel<<<1, 1024, 0, stream>>>(offs, NN);
    scatter_sort_kernel<<<eblocks, 256, 0, stream>>>(esrc, edst, offs, ssrc, NE);

    int lblocks = (NN + NB - 1) / NB;
    sage_fused_kernel<<<lblocks, 256, 0, stream>>>(x, offs, ssrc, w1_l, b1, w1_r, h1, 1);
    sage_fused_kernel<<<lblocks, 256, 0, stream>>>(h1, offs, ssrc, w2_l, b2, w2_r, h2, 0);

    int dblocks = (NP + PB - 1) / PB;
    decode_tiled_kernel<<<dblocks, 256, 0, stream>>>(h2, pu, pv, wd1, bd1, wd2, bd2,
                                                     (float*)d_out);
}

// Round 3
// 1667.302 us; speedup vs baseline: 5.0220x; 1.0843x over previous
//
#include <hip/hip_runtime.h>

#define NN 100000
#define NE 1600000
#define NP 500000
#define C 128
#define NB 16    // nodes per block (6250 blocks exactly; 100000 % 16 == 0)

// ---------- counting sort: histogram ----------
__global__ void hist_kernel(const int* __restrict__ dst, int* __restrict__ cnt, int nE) {
    int e = blockIdx.x * blockDim.x + threadIdx.x;
    if (e < nE) atomicAdd(&cnt[dst[e]], 1);
}

// ---------- single-block exclusive scan over NN ints (in place) ----------
__global__ void scan_kernel(int* __restrict__ cnt, int n) {
    __shared__ int tsum[1024];
    int tid = threadIdx.x;
    int chunk = (n + 1023) / 1024;
    int lo = tid * chunk;
    int hi = min(lo + chunk, n);
    int s = 0;
    for (int i = lo; i < hi; ++i) s += cnt[i];
    tsum[tid] = s;
    __syncthreads();
    for (int off = 1; off < 1024; off <<= 1) {
        int v = (tid >= off) ? tsum[tid - off] : 0;
        __syncthreads();
        tsum[tid] += v;
        __syncthreads();
    }
    int base = (tid == 0) ? 0 : tsum[tid - 1];
    for (int i = lo; i < hi; ++i) {
        int c = cnt[i];
        cnt[i] = base;
        base += c;
    }
}

// ---------- scatter src ids into CSR order; offs[i] becomes end-offset ----------
__global__ void scatter_sort_kernel(const int* __restrict__ src, const int* __restrict__ dst,
                                    int* __restrict__ offs, int* __restrict__ ssrc, int nE) {
    int e = blockIdx.x * blockDim.x + threadIdx.x;
    if (e >= nE) return;
    int pos = atomicAdd(&offs[dst[e]], 1);
    ssrc[pos] = src[e];
}

// ---------- layer 1: mean-aggregate + SAGE + ReLU ----------
// 256 threads, NB=16 nodes/block; group g=tid>>7 handles 8 nodes, c=tid&127.
__global__ __launch_bounds__(256) void sage1_kernel(
        const float* __restrict__ x,
        const int* __restrict__ offs, const int* __restrict__ ssrc,
        const float* __restrict__ wl, const float* __restrict__ bias,
        const float* __restrict__ wr, float* __restrict__ h1) {
    __shared__ float sm[NB][C];
    __shared__ float sx[NB][C];
    int tid = threadIdx.x;
    int c = tid & (C - 1);
    int g = tid >> 7;
    int node0 = blockIdx.x * NB;
    int nb0 = g * 8;

    for (int i = 0; i < 8; ++i) {
        int li = nb0 + i;
        int n = node0 + li;
        int start = (n == 0) ? 0 : offs[n - 1];
        int end = offs[n];
        float acc = 0.0f;
        for (int e = start; e < end; ++e) acc += x[(size_t)ssrc[e] * C + c];
        sm[li][c] = acc / fmaxf((float)(end - start), 1.0f);
        sx[li][c] = x[(size_t)n * C + c];
    }
    __syncthreads();

    float acc[8];
    float bv = bias[c];
#pragma unroll
    for (int i = 0; i < 8; ++i) acc[i] = bv;

    for (int k = 0; k < C; k += 4) {
        float4 wlv, wrv;
        wlv.x = wl[(k + 0) * C + c]; wlv.y = wl[(k + 1) * C + c];
        wlv.z = wl[(k + 2) * C + c]; wlv.w = wl[(k + 3) * C + c];
        wrv.x = wr[(k + 0) * C + c]; wrv.y = wr[(k + 1) * C + c];
        wrv.z = wr[(k + 2) * C + c]; wrv.w = wr[(k + 3) * C + c];
#pragma unroll
        for (int i = 0; i < 8; ++i) {
            float4 m  = *(const float4*)&sm[nb0 + i][k];
            float4 xv = *(const float4*)&sx[nb0 + i][k];
            acc[i] += m.x * wlv.x + m.y * wlv.y + m.z * wlv.z + m.w * wlv.w;
            acc[i] += xv.x * wrv.x + xv.y * wrv.y + xv.z * wrv.z + xv.w * wrv.w;
        }
    }
#pragma unroll
    for (int i = 0; i < 8; ++i) {
        h1[(size_t)(node0 + nb0 + i) * C + c] = fmaxf(acc[i], 0.0f);
    }
}

// ---------- layer 2 fused with decode-weight projection ----------
// computes h2 = mean@w2_l + b2 + h1@w2_r (registers -> LDS), then
// a[n] = h2[n]@wd1[0:128] + bd1, b[n] = h2[n]@wd1[128:256]. h2 never stored.
__global__ __launch_bounds__(256) void sage2_ab_kernel(
        const float* __restrict__ h1,
        const int* __restrict__ offs, const int* __restrict__ ssrc,
        const float* __restrict__ wl, const float* __restrict__ bias,
        const float* __restrict__ wr,
        const float* __restrict__ wd1, const float* __restrict__ bd1,
        float* __restrict__ a, float* __restrict__ b) {
    __shared__ float sm[NB][C];
    __shared__ float sx[NB][C];
    int tid = threadIdx.x;
    int c = tid & (C - 1);
    int g = tid >> 7;
    int node0 = blockIdx.x * NB;
    int nb0 = g * 8;

    for (int i = 0; i < 8; ++i) {
        int li = nb0 + i;
        int n = node0 + li;
        int start = (n == 0) ? 0 : offs[n - 1];
        int end = offs[n];
        float acc = 0.0f;
        for (int e = start; e < end; ++e) acc += h1[(size_t)ssrc[e] * C + c];
        sm[li][c] = acc / fmaxf((float)(end - start), 1.0f);
        sx[li][c] = h1[(size_t)n * C + c];
    }
    __syncthreads();

    float acc[8];
    float bv = bias[c];
#pragma unroll
    for (int i = 0; i < 8; ++i) acc[i] = bv;

    for (int k = 0; k < C; k += 4) {
        float4 wlv, wrv;
        wlv.x = wl[(k + 0) * C + c]; wlv.y = wl[(k + 1) * C + c];
        wlv.z = wl[(k + 2) * C + c]; wlv.w = wl[(k + 3) * C + c];
        wrv.x = wr[(k + 0) * C + c]; wrv.y = wr[(k + 1) * C + c];
        wrv.z = wr[(k + 2) * C + c]; wrv.w = wr[(k + 3) * C + c];
#pragma unroll
        for (int i = 0; i < 8; ++i) {
            float4 m  = *(const float4*)&sm[nb0 + i][k];
            float4 xv = *(const float4*)&sx[nb0 + i][k];
            acc[i] += m.x * wlv.x + m.y * wlv.y + m.z * wlv.z + m.w * wlv.w;
            acc[i] += xv.x * wrv.x + xv.y * wrv.y + xv.z * wrv.z + xv.w * wrv.w;
        }
    }
    __syncthreads();          // done reading sm/sx
    // stash h2 rows in sm (reuse)
#pragma unroll
    for (int i = 0; i < 8; ++i) sm[nb0 + i][c] = acc[i];
    __syncthreads();

    float aacc[8], bacc[8];
    float b1v = bd1[c];
#pragma unroll
    for (int i = 0; i < 8; ++i) { aacc[i] = b1v; bacc[i] = 0.0f; }

    for (int k = 0; k < C; k += 4) {
        float4 wt, wb;
        wt.x = wd1[(k + 0) * C + c]; wt.y = wd1[(k + 1) * C + c];
        wt.z = wd1[(k + 2) * C + c]; wt.w = wd1[(k + 3) * C + c];
        wb.x = wd1[(128 + k + 0) * C + c]; wb.y = wd1[(128 + k + 1) * C + c];
        wb.z = wd1[(128 + k + 2) * C + c]; wb.w = wd1[(128 + k + 3) * C + c];
#pragma unroll
        for (int i = 0; i < 8; ++i) {
            float4 h = *(const float4*)&sm[nb0 + i][k];
            aacc[i] += h.x * wt.x + h.y * wt.y + h.z * wt.z + h.w * wt.w;
            bacc[i] += h.x * wb.x + h.y * wb.y + h.z * wb.z + h.w * wb.w;
        }
    }
#pragma unroll
    for (int i = 0; i < 8; ++i) {
        size_t row = (size_t)(node0 + nb0 + i) * C + c;
        a[row] = aacc[i];
        b[row] = bacc[i];
    }
}

// ---------- decode: out[p] = relu(a[u]+b[v]) . wd2 + bd2 ----------
// one wave per pair per iteration; lane handles 2 channels (float2).
__global__ __launch_bounds__(256) void decode_kernel(
        const float* __restrict__ a, const float* __restrict__ b,
        const int* __restrict__ pu, const int* __restrict__ pv,
        const float* __restrict__ wd2, const float* __restrict__ bd2,
        float* __restrict__ out) {
    int gwave = (blockIdx.x * 256 + threadIdx.x) >> 6;
    int lane = threadIdx.x & 63;
    int nw = (gridDim.x * 256) >> 6;
    float2 w2 = *(const float2*)&wd2[lane * 2];
    float bout = bd2[0];
    for (int p = gwave; p < NP; p += nw) {
        int u = pu[p], v = pv[p];
        float2 av = *(const float2*)(a + (size_t)u * C + lane * 2);
        float2 bv = *(const float2*)(b + (size_t)v * C + lane * 2);
        float s = fmaxf(av.x + bv.x, 0.0f) * w2.x + fmaxf(av.y + bv.y, 0.0f) * w2.y;
#pragma unroll
        for (int off = 32; off; off >>= 1) s += __shfl_down(s, off, 64);
        if (lane == 0) out[p] = s + bout;
    }
}

extern "C" void kernel_launch(void* const* d_in, const int* in_sizes, int n_in,
                              void* d_out, int out_size, void* d_ws, size_t ws_size,
                              hipStream_t stream) {
    const float* x    = (const float*)d_in[0];
    const float* w1_l = (const float*)d_in[1];
    const float* b1   = (const float*)d_in[2];
    const float* w1_r = (const float*)d_in[3];
    const float* w2_l = (const float*)d_in[4];
    const float* b2   = (const float*)d_in[5];
    const float* w2_r = (const float*)d_in[6];
    const float* wd1  = (const float*)d_in[7];
    const float* bd1  = (const float*)d_in[8];
    const float* wd2  = (const float*)d_in[9];
    const float* bd2  = (const float*)d_in[10];
    const int* edge_index = (const int*)d_in[11];
    const int* edge_pairs = (const int*)d_in[12];

    const int* esrc = edge_index;
    const int* edst = edge_index + NE;
    const int* pu = edge_pairs;
    const int* pv = edge_pairs + NP;

    // ws layout (f32/int): offs | ssrc | h1[N*C] | a[N*C] | b[N*C]  (~160 MB)
    int* offs = (int*)d_ws;
    int* ssrc = offs + ((NN + 255) & ~255);
    float* h1 = (float*)(ssrc + ((NE + 255) & ~255));
    float* a  = h1 + (size_t)NN * C;
    float* b  = a + (size_t)NN * C;

    hipMemsetAsync(offs, 0, sizeof(int) * NN, stream);

    int eblocks = (NE + 255) / 256;
    hist_kernel<<<eblocks, 256, 0, stream>>>(edst, offs, NE);
    scan_kernel<<<1, 1024, 0, stream>>>(offs, NN);
    scatter_sort_kernel<<<eblocks, 256, 0, stream>>>(esrc, edst, offs, ssrc, NE);

    int lblocks = NN / NB;
    sage1_kernel<<<lblocks, 256, 0, stream>>>(x, offs, ssrc, w1_l, b1, w1_r, h1);
    sage2_ab_kernel<<<lblocks, 256, 0, stream>>>(h1, offs, ssrc, w2_l, b2, w2_r,
                                                 wd1, bd1, a, b);

    decode_kernel<<<2048, 256, 0, stream>>>(a, b, pu, pv, wd2, bd2, (float*)d_out);
}

// Round 4
// 1083.723 us; speedup vs baseline: 7.7263x; 1.5385x over previous
//
#include <hip/hip_runtime.h>

#define NN 100000
#define NE 1600000
#define NP 500000
#define C 128
#define TNB 32   // nodes per transform block (100000/32 = 3125 exactly)

// ---------- counting sort: histogram ----------
__global__ void hist_kernel(const int* __restrict__ dst, int* __restrict__ cnt, int nE) {
    int e = blockIdx.x * blockDim.x + threadIdx.x;
    if (e < nE) atomicAdd(&cnt[dst[e]], 1);
}

// ---------- single-block exclusive scan over NN ints (in place) ----------
__global__ void scan_kernel(int* __restrict__ cnt, int n) {
    __shared__ int tsum[1024];
    int tid = threadIdx.x;
    int chunk = (n + 1023) / 1024;
    int lo = tid * chunk;
    int hi = min(lo + chunk, n);
    int s = 0;
    for (int i = lo; i < hi; ++i) s += cnt[i];
    tsum[tid] = s;
    __syncthreads();
    for (int off = 1; off < 1024; off <<= 1) {
        int v = (tid >= off) ? tsum[tid - off] : 0;
        __syncthreads();
        tsum[tid] += v;
        __syncthreads();
    }
    int base = (tid == 0) ? 0 : tsum[tid - 1];
    for (int i = lo; i < hi; ++i) {
        int c = cnt[i];
        cnt[i] = base;
        base += c;
    }
}

// ---------- scatter src ids into CSR order; offs[i] becomes end-offset ----------
__global__ void scatter_sort_kernel(const int* __restrict__ src, const int* __restrict__ dst,
                                    int* __restrict__ offs, int* __restrict__ ssrc, int nE) {
    int e = blockIdx.x * blockDim.x + threadIdx.x;
    if (e >= nE) return;
    int pos = atomicAdd(&offs[dst[e]], 1);
    ssrc[pos] = src[e];
}

// ---------- compose decode projection into layer-2 weights ----------
// Wma = w2l@wt, Wmb = w2l@wb, Wha = w2r@wt, Whb = w2r@wb  (wt/wb = wd1 halves)
// ba = b2@wt + bd1, bb = b2@wb
__global__ void compose_kernel(const float* __restrict__ w2l, const float* __restrict__ w2r,
                               const float* __restrict__ b2,
                               const float* __restrict__ wd1, const float* __restrict__ bd1,
                               float* __restrict__ wcomp, float* __restrict__ bcomp) {
    int c = threadIdx.x;
    int k = blockIdx.x;
    if (k < C) {
        float wma = 0, wmb = 0, wha = 0, whb = 0;
        for (int j = 0; j < C; ++j) {
            float wt = wd1[j * C + c];
            float wb = wd1[(C + j) * C + c];
            float l = w2l[k * C + j];
            float r = w2r[k * C + j];
            wma += l * wt; wmb += l * wb;
            wha += r * wt; whb += r * wb;
        }
        wcomp[0 * C * C + k * C + c] = wma;   // Wma
        wcomp[1 * C * C + k * C + c] = wha;   // Wha
        wcomp[2 * C * C + k * C + c] = wmb;   // Wmb
        wcomp[3 * C * C + k * C + c] = whb;   // Whb
    } else {
        float ba = bd1[c], bb = 0;
        for (int j = 0; j < C; ++j) {
            float bj = b2[j];
            ba += bj * wd1[j * C + c];
            bb += bj * wd1[(C + j) * C + c];
        }
        bcomp[c] = ba;
        bcomp[C + c] = bb;
    }
}

// ---------- gather mean: one wave per node, lane = channel pair ----------
__global__ __launch_bounds__(256) void gather_mean_kernel(
        const float* __restrict__ xin, const int* __restrict__ offs,
        const int* __restrict__ ssrc, float* __restrict__ mean) {
    int gwave = (blockIdx.x * 256 + threadIdx.x) >> 6;
    int lane = threadIdx.x & 63;
    int nw = (gridDim.x * 256) >> 6;
    for (int n = gwave; n < NN; n += nw) {
        int start = (n == 0) ? 0 : offs[n - 1];
        int end = offs[n];
        float ax = 0.0f, ay = 0.0f;
        int e = start;
        for (; e + 1 < end; e += 2) {
            int s0 = ssrc[e], s1 = ssrc[e + 1];
            float2 v0 = *(const float2*)(xin + (size_t)s0 * C + lane * 2);
            float2 v1 = *(const float2*)(xin + (size_t)s1 * C + lane * 2);
            ax += v0.x + v1.x;
            ay += v0.y + v1.y;
        }
        if (e < end) {
            float2 v = *(const float2*)(xin + (size_t)ssrc[e] * C + lane * 2);
            ax += v.x; ay += v.y;
        }
        float inv = 1.0f / fmaxf((float)(end - start), 1.0f);
        *(float2*)(mean + (size_t)n * C + lane * 2) = make_float2(ax * inv, ay * inv);
    }
}

// ---------- transform layer 1: h1 = relu(mean@wl + x@wr + b) ----------
// 256 threads: cq = (tid&31)*4 channels, grp = tid>>5 -> 4 nodes each, TNB=32.
__global__ __launch_bounds__(256) void transform1_kernel(
        const float* __restrict__ mean, const float* __restrict__ x,
        const float* __restrict__ wl, const float* __restrict__ wr,
        const float* __restrict__ bias, float* __restrict__ h1) {
    __shared__ float sA[TNB][C];
    __shared__ float sB[TNB][C];
    int tid = threadIdx.x;
    int node0 = blockIdx.x * TNB;
#pragma unroll
    for (int q = 0; q < 4; ++q) {
        int p = tid + q * 256;
        int r = p >> 5, c4 = (p & 31) * 4;
        *(float4*)&sA[r][c4] = *(const float4*)(mean + (size_t)(node0 + r) * C + c4);
        *(float4*)&sB[r][c4] = *(const float4*)(x + (size_t)(node0 + r) * C + c4);
    }
    __syncthreads();

    int cq = (tid & 31) * 4;
    int i0 = (tid >> 5) * 4;
    float4 bv = *(const float4*)&bias[cq];
    float4 acc[4] = {bv, bv, bv, bv};

    for (int k = 0; k < C; k += 4) {
        float4 w0 = *(const float4*)&wl[(k + 0) * C + cq];
        float4 w1 = *(const float4*)&wl[(k + 1) * C + cq];
        float4 w2 = *(const float4*)&wl[(k + 2) * C + cq];
        float4 w3 = *(const float4*)&wl[(k + 3) * C + cq];
        float4 u0 = *(const float4*)&wr[(k + 0) * C + cq];
        float4 u1 = *(const float4*)&wr[(k + 1) * C + cq];
        float4 u2 = *(const float4*)&wr[(k + 2) * C + cq];
        float4 u3 = *(const float4*)&wr[(k + 3) * C + cq];
#pragma unroll
        for (int ii = 0; ii < 4; ++ii) {
            float4 m = *(const float4*)&sA[i0 + ii][k];
            float4 xv = *(const float4*)&sB[i0 + ii][k];
            acc[ii].x += m.x * w0.x + m.y * w1.x + m.z * w2.x + m.w * w3.x
                       + xv.x * u0.x + xv.y * u1.x + xv.z * u2.x + xv.w * u3.x;
            acc[ii].y += m.x * w0.y + m.y * w1.y + m.z * w2.y + m.w * w3.y
                       + xv.x * u0.y + xv.y * u1.y + xv.z * u2.y + xv.w * u3.y;
            acc[ii].z += m.x * w0.z + m.y * w1.z + m.z * w2.z + m.w * w3.z
                       + xv.x * u0.z + xv.y * u1.z + xv.z * u2.z + xv.w * u3.z;
            acc[ii].w += m.x * w0.w + m.y * w1.w + m.z * w2.w + m.w * w3.w
                       + xv.x * u0.w + xv.y * u1.w + xv.z * u2.w + xv.w * u3.w;
        }
    }
#pragma unroll
    for (int ii = 0; ii < 4; ++ii) {
        float4 v = acc[ii];
        v.x = fmaxf(v.x, 0.0f); v.y = fmaxf(v.y, 0.0f);
        v.z = fmaxf(v.z, 0.0f); v.w = fmaxf(v.w, 0.0f);
        *(float4*)(h1 + (size_t)(node0 + i0 + ii) * C + cq) = v;
    }
}

// ---------- transform layer 2 (composed): a,b from mean2 and h1 ----------
// a = m@Wma + h1@Wha + ba ; b = m@Wmb + h1@Whb + bb. Writes a in place over mean.
__global__ __launch_bounds__(256) void transform2_kernel(
        float* __restrict__ abuf /* in: mean2, out: a */,
        const float* __restrict__ h1,
        const float* __restrict__ wcomp, const float* __restrict__ bcomp,
        float* __restrict__ bbuf) {
    __shared__ float sA[TNB][C];
    __shared__ float sB[TNB][C];
    int tid = threadIdx.x;
    int node0 = blockIdx.x * TNB;
#pragma unroll
    for (int q = 0; q < 4; ++q) {
        int p = tid + q * 256;
        int r = p >> 5, c4 = (p & 31) * 4;
        *(float4*)&sA[r][c4] = *(const float4*)(abuf + (size_t)(node0 + r) * C + c4);
        *(float4*)&sB[r][c4] = *(const float4*)(h1 + (size_t)(node0 + r) * C + c4);
    }
    __syncthreads();

    int cq = (tid & 31) * 4;
    int i0 = (tid >> 5) * 4;
    const float* Wma = wcomp;
    const float* Wha = wcomp + C * C;
    const float* Wmb = wcomp + 2 * C * C;
    const float* Whb = wcomp + 3 * C * C;
    float4 bav = *(const float4*)&bcomp[cq];
    float4 bbv = *(const float4*)&bcomp[C + cq];
    float4 acca[4] = {bav, bav, bav, bav};
    float4 accb[4] = {bbv, bbv, bbv, bbv};

    for (int k = 0; k < C; k += 4) {
        float4 m[4], h[4];
#pragma unroll
        for (int ii = 0; ii < 4; ++ii) {
            m[ii] = *(const float4*)&sA[i0 + ii][k];
            h[ii] = *(const float4*)&sB[i0 + ii][k];
        }
        {   // a-phase
            float4 w0 = *(const float4*)&Wma[(k + 0) * C + cq];
            float4 w1 = *(const float4*)&Wma[(k + 1) * C + cq];
            float4 w2 = *(const float4*)&Wma[(k + 2) * C + cq];
            float4 w3 = *(const float4*)&Wma[(k + 3) * C + cq];
            float4 u0 = *(const float4*)&Wha[(k + 0) * C + cq];
            float4 u1 = *(const float4*)&Wha[(k + 1) * C + cq];
            float4 u2 = *(const float4*)&Wha[(k + 2) * C + cq];
            float4 u3 = *(const float4*)&Wha[(k + 3) * C + cq];
#pragma unroll
            for (int ii = 0; ii < 4; ++ii) {
                acca[ii].x += m[ii].x * w0.x + m[ii].y * w1.x + m[ii].z * w2.x + m[ii].w * w3.x
                            + h[ii].x * u0.x + h[ii].y * u1.x + h[ii].z * u2.x + h[ii].w * u3.x;
                acca[ii].y += m[ii].x * w0.y + m[ii].y * w1.y + m[ii].z * w2.y + m[ii].w * w3.y
                            + h[ii].x * u0.y + h[ii].y * u1.y + h[ii].z * u2.y + h[ii].w * u3.y;
                acca[ii].z += m[ii].x * w0.z + m[ii].y * w1.z + m[ii].z * w2.z + m[ii].w * w3.z
                            + h[ii].x * u0.z + h[ii].y * u1.z + h[ii].z * u2.z + h[ii].w * u3.z;
                acca[ii].w += m[ii].x * w0.w + m[ii].y * w1.w + m[ii].z * w2.w + m[ii].w * w3.w
                            + h[ii].x * u0.w + h[ii].y * u1.w + h[ii].z * u2.w + h[ii].w * u3.w;
            }
        }
        {   // b-phase
            float4 w0 = *(const float4*)&Wmb[(k + 0) * C + cq];
            float4 w1 = *(const float4*)&Wmb[(k + 1) * C + cq];
            float4 w2 = *(const float4*)&Wmb[(k + 2) * C + cq];
            float4 w3 = *(const float4*)&Wmb[(k + 3) * C + cq];
            float4 u0 = *(const float4*)&Whb[(k + 0) * C + cq];
            float4 u1 = *(const float4*)&Whb[(k + 1) * C + cq];
            float4 u2 = *(const float4*)&Whb[(k + 2) * C + cq];
            float4 u3 = *(const float4*)&Whb[(k + 3) * C + cq];
#pragma unroll
            for (int ii = 0; ii < 4; ++ii) {
                accb[ii].x += m[ii].x * w0.x + m[ii].y * w1.x + m[ii].z * w2.x + m[ii].w * w3.x
                            + h[ii].x * u0.x + h[ii].y * u1.x + h[ii].z * u2.x + h[ii].w * u3.x;
                accb[ii].y += m[ii].x * w0.y + m[ii].y * w1.y + m[ii].z * w2.y + m[ii].w * w3.y
                            + h[ii].x * u0.y + h[ii].y * u1.y + h[ii].z * u2.y + h[ii].w * u3.y;
                accb[ii].z += m[ii].x * w0.z + m[ii].y * w1.z + m[ii].z * w2.z + m[ii].w * w3.z
                            + h[ii].x * u0.z + h[ii].y * u1.z + h[ii].z * u2.z + h[ii].w * u3.z;
                accb[ii].w += m[ii].x * w0.w + m[ii].y * w1.w + m[ii].z * w2.w + m[ii].w * w3.w
                            + h[ii].x * u0.w + h[ii].y * u1.w + h[ii].z * u2.w + h[ii].w * u3.w;
            }
        }
    }
#pragma unroll
    for (int ii = 0; ii < 4; ++ii) {
        size_t row = (size_t)(node0 + i0 + ii) * C + cq;
        *(float4*)(abuf + row) = acca[ii];
        *(float4*)(bbuf + row) = accb[ii];
    }
}

// ---------- decode: half-wave (32 lanes x float4) per pair ----------
__global__ __launch_bounds__(256) void decode_kernel(
        const float* __restrict__ a, const float* __restrict__ b,
        const int* __restrict__ pu, const int* __restrict__ pv,
        const float* __restrict__ wd2, const float* __restrict__ bd2,
        float* __restrict__ out) {
    int gid = blockIdx.x * 256 + threadIdx.x;
    int hw = gid >> 5;
    int lane = threadIdx.x & 31;
    int nhw = (gridDim.x * 256) >> 5;
    float4 w2 = *(const float4*)&wd2[lane * 4];
    float bout = bd2[0];
    for (int p = hw; p < NP; p += nhw) {
        int u = pu[p], v = pv[p];
        float4 av = *(const float4*)(a + (size_t)u * C + lane * 4);
        float4 bv = *(const float4*)(b + (size_t)v * C + lane * 4);
        float s = fmaxf(av.x + bv.x, 0.0f) * w2.x + fmaxf(av.y + bv.y, 0.0f) * w2.y
                + fmaxf(av.z + bv.z, 0.0f) * w2.z + fmaxf(av.w + bv.w, 0.0f) * w2.w;
#pragma unroll
        for (int off = 16; off; off >>= 1) s += __shfl_down(s, off, 32);
        if (lane == 0) out[p] = s + bout;
    }
}

extern "C" void kernel_launch(void* const* d_in, const int* in_sizes, int n_in,
                              void* d_out, int out_size, void* d_ws, size_t ws_size,
                              hipStream_t stream) {
    const float* x    = (const float*)d_in[0];
    const float* w1_l = (const float*)d_in[1];
    const float* b1   = (const float*)d_in[2];
    const float* w1_r = (const float*)d_in[3];
    const float* w2_l = (const float*)d_in[4];
    const float* b2   = (const float*)d_in[5];
    const float* w2_r = (const float*)d_in[6];
    const float* wd1  = (const float*)d_in[7];
    const float* bd1  = (const float*)d_in[8];
    const float* wd2  = (const float*)d_in[9];
    const float* bd2  = (const float*)d_in[10];
    const int* edge_index = (const int*)d_in[11];
    const int* edge_pairs = (const int*)d_in[12];

    const int* esrc = edge_index;
    const int* edst = edge_index + NE;
    const int* pu = edge_pairs;
    const int* pv = edge_pairs + NP;

    // ws: offs | ssrc | h1[N*C] | abuf[N*C] | bbuf[N*C] | wcomp[4*C*C] | bcomp[2*C]
    int* offs = (int*)d_ws;
    int* ssrc = offs + ((NN + 255) & ~255);
    float* h1   = (float*)(ssrc + NE);
    float* abuf = h1 + (size_t)NN * C;
    float* bbuf = abuf + (size_t)NN * C;
    float* wcomp = bbuf + (size_t)NN * C;
    float* bcomp = wcomp + 4 * C * C;

    hipMemsetAsync(offs, 0, sizeof(int) * NN, stream);

    int eblocks = (NE + 255) / 256;
    hist_kernel<<<eblocks, 256, 0, stream>>>(edst, offs, NE);
    scan_kernel<<<1, 1024, 0, stream>>>(offs, NN);
    scatter_sort_kernel<<<eblocks, 256, 0, stream>>>(esrc, edst, offs, ssrc, NE);

    compose_kernel<<<C + 1, C, 0, stream>>>(w2_l, w2_r, b2, wd1, bd1, wcomp, bcomp);

    gather_mean_kernel<<<6144, 256, 0, stream>>>(x, offs, ssrc, abuf);
    transform1_kernel<<<NN / TNB, 256, 0, stream>>>(abuf, x, w1_l, w1_r, b1, h1);
    gather_mean_kernel<<<6144, 256, 0, stream>>>(h1, offs, ssrc, abuf);
    transform2_kernel<<<NN / TNB, 256, 0, stream>>>(abuf, h1, wcomp, bcomp, bbuf);

    decode_kernel<<<4096, 256, 0, stream>>>(abuf, bbuf, pu, pv, wd2, bd2, (float*)d_out);
}

// Round 5
// 838.452 us; speedup vs baseline: 9.9864x; 1.2925x over previous
//
#include <hip/hip_runtime.h>
#include <hip/hip_bf16.h>

#define NN 100000
#define NE 1600000
#define NP 500000
#define C 128

typedef __attribute__((ext_vector_type(8))) short bf16x8;
typedef __attribute__((ext_vector_type(4))) float f32x4;

__device__ inline unsigned short bfbits(float x) {
    __hip_bfloat16 h = __float2bfloat16(x);
    union { __hip_bfloat16 h; unsigned short u; } v; v.h = h;
    return v.u;
}
__device__ inline float bf2f(unsigned short b) {
    return __uint_as_float(((unsigned)b) << 16);
}

// split 8 consecutive f32 into bf16 hi + bf16 lo fragments
__device__ inline void split8(const float* p, bf16x8& hi, bf16x8& lo) {
    union { unsigned short s[8]; bf16x8 v; } uh, ul;
    f32x4 a = *(const f32x4*)p;
    f32x4 b = *(const f32x4*)(p + 4);
    float xs[8] = {a.x, a.y, a.z, a.w, b.x, b.y, b.z, b.w};
#pragma unroll
    for (int j = 0; j < 8; ++j) {
        unsigned short h = bfbits(xs[j]);
        uh.s[j] = h;
        ul.s[j] = bfbits(xs[j] - bf2f(h));
    }
    hi = uh.v;
    lo = ul.v;
}

// ---------- counting sort: histogram ----------
__global__ void hist_kernel(const int* __restrict__ dst, int* __restrict__ cnt, int nE) {
    int e = blockIdx.x * blockDim.x + threadIdx.x;
    if (e < nE) atomicAdd(&cnt[dst[e]], 1);
}

// ---------- single-block exclusive scan over NN ints (in place) ----------
__global__ void scan_kernel(int* __restrict__ cnt, int n) {
    __shared__ int tsum[1024];
    int tid = threadIdx.x;
    int chunk = (n + 1023) / 1024;
    int lo = tid * chunk;
    int hi = min(lo + chunk, n);
    int s = 0;
    for (int i = lo; i < hi; ++i) s += cnt[i];
    tsum[tid] = s;
    __syncthreads();
    for (int off = 1; off < 1024; off <<= 1) {
        int v = (tid >= off) ? tsum[tid - off] : 0;
        __syncthreads();
        tsum[tid] += v;
        __syncthreads();
    }
    int base = (tid == 0) ? 0 : tsum[tid - 1];
    for (int i = lo; i < hi; ++i) {
        int c = cnt[i];
        cnt[i] = base;
        base += c;
    }
}

// ---------- scatter src ids into CSR order; offs[i] becomes end-offset ----------
__global__ void scatter_sort_kernel(const int* __restrict__ src, const int* __restrict__ dst,
                                    int* __restrict__ offs, int* __restrict__ ssrc, int nE) {
    int e = blockIdx.x * blockDim.x + threadIdx.x;
    if (e >= nE) return;
    int pos = atomicAdd(&offs[dst[e]], 1);
    ssrc[pos] = src[e];
}

// ---------- compose decode projection into layer-2 weights ----------
__global__ void compose_kernel(const float* __restrict__ w2l, const float* __restrict__ w2r,
                               const float* __restrict__ b2,
                               const float* __restrict__ wd1, const float* __restrict__ bd1,
                               float* __restrict__ wcomp, float* __restrict__ bcomp) {
    int c = threadIdx.x;
    int k = blockIdx.x;
    if (k < C) {
        float wma = 0, wmb = 0, wha = 0, whb = 0;
        for (int j = 0; j < C; ++j) {
            float wt = wd1[j * C + c];
            float wb = wd1[(C + j) * C + c];
            float l = w2l[k * C + j];
            float r = w2r[k * C + j];
            wma += l * wt; wmb += l * wb;
            wha += r * wt; whb += r * wb;
        }
        wcomp[0 * C * C + k * C + c] = wma;   // k<128, n<128  (m -> a)
        wcomp[1 * C * C + k * C + c] = wha;   // k>=128, n<128 (h -> a)
        wcomp[2 * C * C + k * C + c] = wmb;   // k<128, n>=128 (m -> b)
        wcomp[3 * C * C + k * C + c] = whb;   // k>=128, n>=128(h -> b)
    } else {
        float ba = bd1[c], bb = 0;
        for (int j = 0; j < C; ++j) {
            float bj = b2[j];
            ba += bj * wd1[j * C + c];
            bb += bj * wd1[(C + j) * C + c];
        }
        bcomp[c] = ba;
        bcomp[C + c] = bb;
    }
}

// ---------- pack W1=[wl;wr] (K=256,N=128) into B-fragment layout, bf16 hi/lo ----------
// flat idx = ((nf*8 + kf)*64 + l)*8 + j ; element = W[kf*32 + (l>>4)*8 + j][nf*16 + (l&15)]
__global__ void pack_w1_kernel(const float* __restrict__ wl, const float* __restrict__ wr,
                               short* __restrict__ Wh, short* __restrict__ Wl) {
    int t = blockIdx.x * 256 + threadIdx.x;   // [0, 256*128)
    int j = t & 7, l = (t >> 3) & 63;
    int kf = (t >> 9) & 7;
    int nf = t >> 12;                          // 0..7
    int k = kf * 32 + ((l >> 4) << 3) + j;
    int n = nf * 16 + (l & 15);
    float w = (k < C) ? wl[k * C + n] : wr[(k - C) * C + n];
    unsigned short h = bfbits(w);
    Wh[t] = (short)h;
    Wl[t] = (short)bfbits(w - bf2f(h));
}

// ---------- pack composed W2 (K=256,N=256) from wcomp ----------
__global__ void pack_w2_kernel(const float* __restrict__ wcomp,
                               short* __restrict__ Wh, short* __restrict__ Wl) {
    int t = blockIdx.x * 256 + threadIdx.x;   // [0, 256*256)
    int j = t & 7, l = (t >> 3) & 63;
    int kf = (t >> 9) & 7;
    int nf = t >> 12;                          // 0..15
    int k = kf * 32 + ((l >> 4) << 3) + j;
    int n = nf * 16 + (l & 15);
    int sel = (k >= C ? 1 : 0) + (n >= C ? 2 : 0);
    float w = wcomp[sel * C * C + (k & (C - 1)) * C + (n & (C - 1))];
    unsigned short h = bfbits(w);
    Wh[t] = (short)h;
    Wl[t] = (short)bfbits(w - bf2f(h));
}

// ---------- gather mean: one wave per node, lane = channel pair ----------
__global__ __launch_bounds__(256) void gather_mean_kernel(
        const float* __restrict__ xin, const int* __restrict__ offs,
        const int* __restrict__ ssrc, float* __restrict__ mean) {
    int gwave = (blockIdx.x * 256 + threadIdx.x) >> 6;
    int lane = threadIdx.x & 63;
    int nw = (gridDim.x * 256) >> 6;
    for (int n = gwave; n < NN; n += nw) {
        int start = (n == 0) ? 0 : offs[n - 1];
        int end = offs[n];
        float ax = 0.0f, ay = 0.0f;
        int e = start;
        for (; e + 1 < end; e += 2) {
            int s0 = ssrc[e], s1 = ssrc[e + 1];
            float2 v0 = *(const float2*)(xin + (size_t)s0 * C + lane * 2);
            float2 v1 = *(const float2*)(xin + (size_t)s1 * C + lane * 2);
            ax += v0.x + v1.x;
            ay += v0.y + v1.y;
        }
        if (e < end) {
            float2 v = *(const float2*)(xin + (size_t)ssrc[e] * C + lane * 2);
            ax += v.x; ay += v.y;
        }
        float inv = 1.0f / fmaxf((float)(end - start), 1.0f);
        *(float2*)(mean + (size_t)n * C + lane * 2) = make_float2(ax * inv, ay * inv);
    }
}

// ---------- MFMA transform: Y[NN x NF*16] = [A0|A1][NN x 256] @ W + bias ----------
// bf16x3: A=Ah+Al, B=Bh+Bl, Y ~= Ah*Bh + Al*Bh + Ah*Bl (f32 accumulate).
// Wave owns 32 rows (2 M-frags), loops all NF col-frags. No LDS, no barriers.
// Outputs may alias A0/A1: each wave reads only its own rows before writing them.
template<int NF, int RELU>
__global__ __launch_bounds__(256, 2) void mfma_transform_kernel(
        const float* A0, const float* A1,
        const short* __restrict__ Bh, const short* __restrict__ Bl,
        const float* __restrict__ bias,
        float* O0, float* O1) {
    constexpr int KF = 8;
    int tid = threadIdx.x;
    int w = tid >> 6, l = tid & 63;
    int m0 = blockIdx.x * 128 + w * 32;
    int lr = l & 15;                 // A row / C col within frag
    int lk = (l >> 4) * 8;           // k offset within 32-frag

    f32x4 acc[2][NF];
#pragma unroll
    for (int ms = 0; ms < 2; ++ms)
#pragma unroll
        for (int nf = 0; nf < NF; ++nf)
            acc[ms][nf] = (f32x4){0.0f, 0.0f, 0.0f, 0.0f};

    const bf16x8* Bhp = (const bf16x8*)Bh;
    const bf16x8* Blp = (const bf16x8*)Bl;

#pragma unroll
    for (int kf = 0; kf < KF; ++kf) {
        const float* Asrc = (kf < 4) ? A0 : A1;
        int kofs = (kf & 3) * 32 + lk;
        bf16x8 ah[2], al[2];
#pragma unroll
        for (int ms = 0; ms < 2; ++ms) {
            int r = m0 + ms * 16 + lr;
            r = (r < NN) ? r : (NN - 1);
            split8(Asrc + (size_t)r * C + kofs, ah[ms], al[ms]);
        }
#pragma unroll
        for (int nf = 0; nf < NF; ++nf) {
            bf16x8 bh = Bhp[(nf * KF + kf) * 64 + l];
            bf16x8 bl = Blp[(nf * KF + kf) * 64 + l];
#pragma unroll
            for (int ms = 0; ms < 2; ++ms) {
                acc[ms][nf] = __builtin_amdgcn_mfma_f32_16x16x32_bf16(ah[ms], bh, acc[ms][nf], 0, 0, 0);
                acc[ms][nf] = __builtin_amdgcn_mfma_f32_16x16x32_bf16(al[ms], bh, acc[ms][nf], 0, 0, 0);
                acc[ms][nf] = __builtin_amdgcn_mfma_f32_16x16x32_bf16(ah[ms], bl, acc[ms][nf], 0, 0, 0);
            }
        }
    }

    // epilogue: C/D layout col = lane&15, row = (lane>>4)*4 + i
#pragma unroll
    for (int nf = 0; nf < NF; ++nf) {
        int col = nf * 16 + lr;
        float bv = bias[col];
        float* O = (NF == 8) ? O0 : ((nf < 8) ? O0 : O1);
        int c = (nf & 7) * 16 + lr;
#pragma unroll
        for (int ms = 0; ms < 2; ++ms) {
#pragma unroll
            for (int i = 0; i < 4; ++i) {
                int r = m0 + ms * 16 + (l >> 4) * 4 + i;
                if (r < NN) {
                    float v = acc[ms][nf][i] + bv;
                    if (RELU) v = fmaxf(v, 0.0f);
                    O[(size_t)r * C + c] = v;
                }
            }
        }
    }
}

// ---------- decode: out[p] = relu(a[u]+b[v]) . wd2 + bd2 ----------
__global__ __launch_bounds__(256) void decode_kernel(
        const float* __restrict__ a, const float* __restrict__ b,
        const int* __restrict__ pu, const int* __restrict__ pv,
        const float* __restrict__ wd2, const float* __restrict__ bd2,
        float* __restrict__ out) {
    int gid = blockIdx.x * 256 + threadIdx.x;
    int hw = gid >> 5;
    int lane = threadIdx.x & 31;
    int nhw = (gridDim.x * 256) >> 5;
    float4 w2 = *(const float4*)&wd2[lane * 4];
    float bout = bd2[0];
    for (int p = hw; p < NP; p += nhw) {
        int u = pu[p], v = pv[p];
        float4 av = *(const float4*)(a + (size_t)u * C + lane * 4);
        float4 bv = *(const float4*)(b + (size_t)v * C + lane * 4);
        float s = fmaxf(av.x + bv.x, 0.0f) * w2.x + fmaxf(av.y + bv.y, 0.0f) * w2.y
                + fmaxf(av.z + bv.z, 0.0f) * w2.z + fmaxf(av.w + bv.w, 0.0f) * w2.w;
#pragma unroll
        for (int off = 16; off; off >>= 1) s += __shfl_down(s, off, 32);
        if (lane == 0) out[p] = s + bout;
    }
}

extern "C" void kernel_launch(void* const* d_in, const int* in_sizes, int n_in,
                              void* d_out, int out_size, void* d_ws, size_t ws_size,
                              hipStream_t stream) {
    const float* x    = (const float*)d_in[0];
    const float* w1_l = (const float*)d_in[1];
    const float* b1   = (const float*)d_in[2];
    const float* w1_r = (const float*)d_in[3];
    const float* w2_l = (const float*)d_in[4];
    const float* b2   = (const float*)d_in[5];
    const float* w2_r = (const float*)d_in[6];
    const float* wd1  = (const float*)d_in[7];
    const float* bd1  = (const float*)d_in[8];
    const float* wd2  = (const float*)d_in[9];
    const float* bd2  = (const float*)d_in[10];
    const int* edge_index = (const int*)d_in[11];
    const int* edge_pairs = (const int*)d_in[12];

    const int* esrc = edge_index;
    const int* edst = edge_index + NE;
    const int* pu = edge_pairs;
    const int* pv = edge_pairs + NP;

    // ws: offs | ssrc | mean[N*C] | h1[N*C] | wcomp | bcomp | w1h/l | w2h/l  (~110 MB)
    int* offs = (int*)d_ws;
    int* ssrc = offs + ((NN + 255) & ~255);
    float* mean = (float*)(ssrc + ((NE + 255) & ~255));
    float* h1   = mean + (size_t)NN * C;
    float* wcomp = h1 + (size_t)NN * C;
    float* bcomp = wcomp + 4 * C * C;
    short* w1h = (short*)(bcomp + 2 * C);
    short* w1l = w1h + 256 * 128;
    short* w2h = w1l + 256 * 128;
    short* w2l = w2h + 256 * 256;

    hipMemsetAsync(offs, 0, sizeof(int) * NN, stream);

    int eblocks = (NE + 255) / 256;
    hist_kernel<<<eblocks, 256, 0, stream>>>(edst, offs, NE);
    scan_kernel<<<1, 1024, 0, stream>>>(offs, NN);
    scatter_sort_kernel<<<eblocks, 256, 0, stream>>>(esrc, edst, offs, ssrc, NE);

    compose_kernel<<<C + 1, C, 0, stream>>>(w2_l, w2_r, b2, wd1, bd1, wcomp, bcomp);
    pack_w1_kernel<<<128, 256, 0, stream>>>(w1_l, w1_r, w1h, w1l);
    pack_w2_kernel<<<256, 256, 0, stream>>>(wcomp, w2h, w2l);

    int tblocks = (NN + 127) / 128;   // 782
    gather_mean_kernel<<<6144, 256, 0, stream>>>(x, offs, ssrc, mean);
    mfma_transform_kernel<8, 1><<<tblocks, 256, 0, stream>>>(
        mean, x, w1h, w1l, b1, h1, nullptr);
    gather_mean_kernel<<<6144, 256, 0, stream>>>(h1, offs, ssrc, mean);
    // outputs alias inputs: a -> mean buffer, b -> h1 buffer (safe: per-wave
    // rows are read fully in the K-loop before the epilogue writes them)
    mfma_transform_kernel<16, 0><<<tblocks, 256, 0, stream>>>(
        mean, h1, w2h, w2l, bcomp, mean, h1);

    decode_kernel<<<4096, 256, 0, stream>>>(mean, h1, pu, pv, wd2, bd2, (float*)d_out);
}

// Round 6
// 673.419 us; speedup vs baseline: 12.4338x; 1.2451x over previous
//
#include <hip/hip_runtime.h>
#include <hip/hip_bf16.h>

#define NN 100000
#define NE 1600000
#define NP 500000
#define C 128
#define SCAN_TILE 256
#define NTILES ((NN + SCAN_TILE - 1) / SCAN_TILE)   // 391

typedef __attribute__((ext_vector_type(8))) short bf16x8;
typedef __attribute__((ext_vector_type(4))) float f32x4;

__device__ inline unsigned short bfbits(float x) {
    __hip_bfloat16 h = __float2bfloat16(x);
    union { __hip_bfloat16 h; unsigned short u; } v; v.h = h;
    return v.u;
}
__device__ inline float bf2f(unsigned short b) {
    return __uint_as_float(((unsigned)b) << 16);
}

// split 8 consecutive f32 into bf16 hi + bf16 lo fragments
__device__ inline void split8(const float* p, bf16x8& hi, bf16x8& lo) {
    union { unsigned short s[8]; bf16x8 v; } uh, ul;
    f32x4 a = *(const f32x4*)p;
    f32x4 b = *(const f32x4*)(p + 4);
    float xs[8] = {a.x, a.y, a.z, a.w, b.x, b.y, b.z, b.w};
#pragma unroll
    for (int j = 0; j < 8; ++j) {
        unsigned short h = bfbits(xs[j]);
        uh.s[j] = h;
        ul.s[j] = bfbits(xs[j] - bf2f(h));
    }
    hi = uh.v;
    lo = ul.v;
}

// ---------- counting sort: histogram ----------
__global__ void hist_kernel(const int* __restrict__ dst, int* __restrict__ cnt, int nE) {
    int e = blockIdx.x * blockDim.x + threadIdx.x;
    if (e < nE) atomicAdd(&cnt[dst[e]], 1);
}

// ---------- device-wide exclusive scan, 3 phases ----------
// phase 1: per-tile exclusive scan (in place), tile total -> tsum[b]
__global__ __launch_bounds__(SCAN_TILE) void scan_local_kernel(
        int* __restrict__ cnt, int* __restrict__ tsum, int n) {
    __shared__ int s[SCAN_TILE];
    int tid = threadIdx.x;
    int idx = blockIdx.x * SCAN_TILE + tid;
    int v = (idx < n) ? cnt[idx] : 0;
    s[tid] = v;
    __syncthreads();
    // Hillis-Steele inclusive scan
    for (int off = 1; off < SCAN_TILE; off <<= 1) {
        int t = (tid >= off) ? s[tid - off] : 0;
        __syncthreads();
        s[tid] += t;
        __syncthreads();
    }
    if (idx < n) cnt[idx] = s[tid] - v;          // exclusive
    if (tid == SCAN_TILE - 1) tsum[blockIdx.x] = s[tid];
}

// phase 2: single block exclusive-scans tile totals (NTILES <= 512)
__global__ __launch_bounds__(512) void scan_tiles_kernel(int* __restrict__ tsum) {
    __shared__ int s[512];
    int tid = threadIdx.x;
    int v = (tid < NTILES) ? tsum[tid] : 0;
    s[tid] = v;
    __syncthreads();
    for (int off = 1; off < 512; off <<= 1) {
        int t = (tid >= off) ? s[tid - off] : 0;
        __syncthreads();
        s[tid] += t;
        __syncthreads();
    }
    if (tid < NTILES) tsum[tid] = s[tid] - v;    // exclusive base per tile
}

// phase 3: add tile base
__global__ __launch_bounds__(SCAN_TILE) void scan_add_kernel(
        int* __restrict__ cnt, const int* __restrict__ tsum, int n) {
    int idx = blockIdx.x * SCAN_TILE + threadIdx.x;
    if (idx < n) cnt[idx] += tsum[blockIdx.x];
}

// ---------- scatter src ids into CSR order; offs[i] becomes end-offset ----------
__global__ void scatter_sort_kernel(const int* __restrict__ src, const int* __restrict__ dst,
                                    int* __restrict__ offs, int* __restrict__ ssrc, int nE) {
    int e = blockIdx.x * blockDim.x + threadIdx.x;
    if (e >= nE) return;
    int pos = atomicAdd(&offs[dst[e]], 1);
    ssrc[pos] = src[e];
}

// ---------- compose decode projection into layer-2 weights ----------
__global__ void compose_kernel(const float* __restrict__ w2l, const float* __restrict__ w2r,
                               const float* __restrict__ b2,
                               const float* __restrict__ wd1, const float* __restrict__ bd1,
                               float* __restrict__ wcomp, float* __restrict__ bcomp) {
    int c = threadIdx.x;
    int k = blockIdx.x;
    if (k < C) {
        float wma = 0, wmb = 0, wha = 0, whb = 0;
        for (int j = 0; j < C; ++j) {
            float wt = wd1[j * C + c];
            float wb = wd1[(C + j) * C + c];
            float l = w2l[k * C + j];
            float r = w2r[k * C + j];
            wma += l * wt; wmb += l * wb;
            wha += r * wt; whb += r * wb;
        }
        wcomp[0 * C * C + k * C + c] = wma;
        wcomp[1 * C * C + k * C + c] = wha;
        wcomp[2 * C * C + k * C + c] = wmb;
        wcomp[3 * C * C + k * C + c] = whb;
    } else {
        float ba = bd1[c], bb = 0;
        for (int j = 0; j < C; ++j) {
            float bj = b2[j];
            ba += bj * wd1[j * C + c];
            bb += bj * wd1[(C + j) * C + c];
        }
        bcomp[c] = ba;
        bcomp[C + c] = bb;
    }
}

// ---------- pack W1=[wl;wr] (K=256,N=128) into B-fragment layout, bf16 hi/lo ----------
__global__ void pack_w1_kernel(const float* __restrict__ wl, const float* __restrict__ wr,
                               short* __restrict__ Wh, short* __restrict__ Wl) {
    int t = blockIdx.x * 256 + threadIdx.x;   // [0, 256*128)
    int j = t & 7, l = (t >> 3) & 63;
    int kf = (t >> 9) & 7;
    int nf = t >> 12;                          // 0..7
    int k = kf * 32 + ((l >> 4) << 3) + j;
    int n = nf * 16 + (l & 15);
    float w = (k < C) ? wl[k * C + n] : wr[(k - C) * C + n];
    unsigned short h = bfbits(w);
    Wh[t] = (short)h;
    Wl[t] = (short)bfbits(w - bf2f(h));
}

// ---------- pack composed W2 (K=256,N=256) from wcomp ----------
__global__ void pack_w2_kernel(const float* __restrict__ wcomp,
                               short* __restrict__ Wh, short* __restrict__ Wl) {
    int t = blockIdx.x * 256 + threadIdx.x;   // [0, 256*256)
    int j = t & 7, l = (t >> 3) & 63;
    int kf = (t >> 9) & 7;
    int nf = t >> 12;                          // 0..15
    int k = kf * 32 + ((l >> 4) << 3) + j;
    int n = nf * 16 + (l & 15);
    int sel = (k >= C ? 1 : 0) + (n >= C ? 2 : 0);
    float w = wcomp[sel * C * C + (k & (C - 1)) * C + (n & (C - 1))];
    unsigned short h = bfbits(w);
    Wh[t] = (short)h;
    Wl[t] = (short)bfbits(w - bf2f(h));
}

// ---------- gather mean: half-wave (32 lanes x float4) per node ----------
__global__ __launch_bounds__(256) void gather_mean_kernel(
        const float* __restrict__ xin, const int* __restrict__ offs,
        const int* __restrict__ ssrc, float* __restrict__ mean) {
    int gid = blockIdx.x * 256 + threadIdx.x;
    int hw = gid >> 5;
    int lane = threadIdx.x & 31;
    int nhw = (gridDim.x * 256) >> 5;
    for (int n = hw; n < NN; n += nhw) {
        int start = (n == 0) ? 0 : offs[n - 1];
        int end = offs[n];
        float4 acc = make_float4(0.f, 0.f, 0.f, 0.f);
        int e = start;
        for (; e + 1 < end; e += 2) {
            int s0 = ssrc[e], s1 = ssrc[e + 1];
            float4 v0 = *(const float4*)(xin + (size_t)s0 * C + lane * 4);
            float4 v1 = *(const float4*)(xin + (size_t)s1 * C + lane * 4);
            acc.x += v0.x + v1.x; acc.y += v0.y + v1.y;
            acc.z += v0.z + v1.z; acc.w += v0.w + v1.w;
        }
        if (e < end) {
            float4 v = *(const float4*)(xin + (size_t)ssrc[e] * C + lane * 4);
            acc.x += v.x; acc.y += v.y; acc.z += v.z; acc.w += v.w;
        }
        float inv = 1.0f / fmaxf((float)(end - start), 1.0f);
        acc.x *= inv; acc.y *= inv; acc.z *= inv; acc.w *= inv;
        *(float4*)(mean + (size_t)n * C + lane * 4) = acc;
    }
}

// ---------- MFMA transform: Y[NN x NF*16] = [A0|A1][NN x 256] @ W + bias ----------
template<int NF, int RELU>
__global__ __launch_bounds__(256, 2) void mfma_transform_kernel(
        const float* A0, const float* A1,
        const short* __restrict__ Bh, const short* __restrict__ Bl,
        const float* __restrict__ bias,
        float* O0, float* O1) {
    constexpr int KF = 8;
    int tid = threadIdx.x;
    int w = tid >> 6, l = tid & 63;
    int m0 = blockIdx.x * 128 + w * 32;
    int lr = l & 15;
    int lk = (l >> 4) * 8;

    f32x4 acc[2][NF];
#pragma unroll
    for (int ms = 0; ms < 2; ++ms)
#pragma unroll
        for (int nf = 0; nf < NF; ++nf)
            acc[ms][nf] = (f32x4){0.0f, 0.0f, 0.0f, 0.0f};

    const bf16x8* Bhp = (const bf16x8*)Bh;
    const bf16x8* Blp = (const bf16x8*)Bl;

#pragma unroll
    for (int kf = 0; kf < KF; ++kf) {
        const float* Asrc = (kf < 4) ? A0 : A1;
        int kofs = (kf & 3) * 32 + lk;
        bf16x8 ah[2], al[2];
#pragma unroll
        for (int ms = 0; ms < 2; ++ms) {
            int r = m0 + ms * 16 + lr;
            r = (r < NN) ? r : (NN - 1);
            split8(Asrc + (size_t)r * C + kofs, ah[ms], al[ms]);
        }
#pragma unroll
        for (int nf = 0; nf < NF; ++nf) {
            bf16x8 bh = Bhp[(nf * KF + kf) * 64 + l];
            bf16x8 bl = Blp[(nf * KF + kf) * 64 + l];
#pragma unroll
            for (int ms = 0; ms < 2; ++ms) {
                acc[ms][nf] = __builtin_amdgcn_mfma_f32_16x16x32_bf16(ah[ms], bh, acc[ms][nf], 0, 0, 0);
                acc[ms][nf] = __builtin_amdgcn_mfma_f32_16x16x32_bf16(al[ms], bh, acc[ms][nf], 0, 0, 0);
                acc[ms][nf] = __builtin_amdgcn_mfma_f32_16x16x32_bf16(ah[ms], bl, acc[ms][nf], 0, 0, 0);
            }
        }
    }

#pragma unroll
    for (int nf = 0; nf < NF; ++nf) {
        int col = nf * 16 + lr;
        float bv = bias[col];
        float* O = (NF == 8) ? O0 : ((nf < 8) ? O0 : O1);
        int c = (nf & 7) * 16 + lr;
#pragma unroll
        for (int ms = 0; ms < 2; ++ms) {
#pragma unroll
            for (int i = 0; i < 4; ++i) {
                int r = m0 + ms * 16 + (l >> 4) * 4 + i;
                if (r < NN) {
                    float v = acc[ms][nf][i] + bv;
                    if (RELU) v = fmaxf(v, 0.0f);
                    O[(size_t)r * C + c] = v;
                }
            }
        }
    }
}

// ---------- decode: out[p] = relu(a[u]+b[v]) . wd2 + bd2 ----------
__global__ __launch_bounds__(256) void decode_kernel(
        const float* __restrict__ a, const float* __restrict__ b,
        const int* __restrict__ pu, const int* __restrict__ pv,
        const float* __restrict__ wd2, const float* __restrict__ bd2,
        float* __restrict__ out) {
    int gid = blockIdx.x * 256 + threadIdx.x;
    int hw = gid >> 5;
    int lane = threadIdx.x & 31;
    int nhw = (gridDim.x * 256) >> 5;
    float4 w2 = *(const float4*)&wd2[lane * 4];
    float bout = bd2[0];
    for (int p = hw; p < NP; p += nhw) {
        int u = pu[p], v = pv[p];
        float4 av = *(const float4*)(a + (size_t)u * C + lane * 4);
        float4 bv = *(const float4*)(b + (size_t)v * C + lane * 4);
        float s = fmaxf(av.x + bv.x, 0.0f) * w2.x + fmaxf(av.y + bv.y, 0.0f) * w2.y
                + fmaxf(av.z + bv.z, 0.0f) * w2.z + fmaxf(av.w + bv.w, 0.0f) * w2.w;
#pragma unroll
        for (int off = 16; off; off >>= 1) s += __shfl_down(s, off, 32);
        if (lane == 0) out[p] = s + bout;
    }
}

extern "C" void kernel_launch(void* const* d_in, const int* in_sizes, int n_in,
                              void* d_out, int out_size, void* d_ws, size_t ws_size,
                              hipStream_t stream) {
    const float* x    = (const float*)d_in[0];
    const float* w1_l = (const float*)d_in[1];
    const float* b1   = (const float*)d_in[2];
    const float* w1_r = (const float*)d_in[3];
    const float* w2_l = (const float*)d_in[4];
    const float* b2   = (const float*)d_in[5];
    const float* w2_r = (const float*)d_in[6];
    const float* wd1  = (const float*)d_in[7];
    const float* bd1  = (const float*)d_in[8];
    const float* wd2  = (const float*)d_in[9];
    const float* bd2  = (const float*)d_in[10];
    const int* edge_index = (const int*)d_in[11];
    const int* edge_pairs = (const int*)d_in[12];

    const int* esrc = edge_index;
    const int* edst = edge_index + NE;
    const int* pu = edge_pairs;
    const int* pv = edge_pairs + NP;

    // ws: offs | tsum | ssrc | mean[N*C] | h1[N*C] | wcomp | bcomp | w1h/l | w2h/l
    int* offs = (int*)d_ws;
    int* tsum = offs + ((NN + 255) & ~255);
    int* ssrc = tsum + 512;
    float* mean = (float*)(ssrc + ((NE + 255) & ~255));
    float* h1   = mean + (size_t)NN * C;
    float* wcomp = h1 + (size_t)NN * C;
    float* bcomp = wcomp + 4 * C * C;
    short* w1h = (short*)(bcomp + 2 * C);
    short* w1l = w1h + 256 * 128;
    short* w2h = w1l + 256 * 128;
    short* w2l = w2h + 256 * 256;

    hipMemsetAsync(offs, 0, sizeof(int) * NN, stream);

    int eblocks = (NE + 255) / 256;
    hist_kernel<<<eblocks, 256, 0, stream>>>(edst, offs, NE);
    scan_local_kernel<<<NTILES, SCAN_TILE, 0, stream>>>(offs, tsum, NN);
    scan_tiles_kernel<<<1, 512, 0, stream>>>(tsum);
    scan_add_kernel<<<NTILES, SCAN_TILE, 0, stream>>>(offs, tsum, NN);
    scatter_sort_kernel<<<eblocks, 256, 0, stream>>>(esrc, edst, offs, ssrc, NE);

    compose_kernel<<<C + 1, C, 0, stream>>>(w2_l, w2_r, b2, wd1, bd1, wcomp, bcomp);
    pack_w1_kernel<<<128, 256, 0, stream>>>(w1_l, w1_r, w1h, w1l);
    pack_w2_kernel<<<256, 256, 0, stream>>>(wcomp, w2h, w2l);

    int tblocks = (NN + 127) / 128;   // 782
    gather_mean_kernel<<<6144, 256, 0, stream>>>(x, offs, ssrc, mean);
    mfma_transform_kernel<8, 1><<<tblocks, 256, 0, stream>>>(
        mean, x, w1h, w1l, b1, h1, nullptr);
    gather_mean_kernel<<<6144, 256, 0, stream>>>(h1, offs, ssrc, mean);
    mfma_transform_kernel<16, 0><<<tblocks, 256, 0, stream>>>(
        mean, h1, w2h, w2l, bcomp, mean, h1);

    decode_kernel<<<4096, 256, 0, stream>>>(mean, h1, pu, pv, wd2, bd2, (float*)d_out);
}